// Round 8
// baseline (580.746 us; speedup 1.0000x reference)
//
#include <hip/hip_runtime.h>
#include <hip/hip_bf16.h>

#define NN    100000
#define NEDGE 1250000
constexpr int NW = NEDGE / 16;     // 78125 windows, exact

typedef __attribute__((ext_vector_type(8))) short bf16x8;
typedef __attribute__((ext_vector_type(8))) unsigned short u16x8;
typedef __attribute__((ext_vector_type(4))) float f32x4;

__device__ __forceinline__ short f2bf(float f) {
    unsigned u = __float_as_uint(f);
    u += 0x7FFFu + ((u >> 16) & 1u);   // round-to-nearest-even
    return (short)(u >> 16);
}
__device__ __forceinline__ float bf2f(unsigned short u) {
    return __uint_as_float(((unsigned)u) << 16);
}

// ws layout (bytes)
constexpr size_t OFF_Q    = 0;                                   // f32 [NN*64]
constexpr size_t OFF_KB   = OFF_Q    + (size_t)NN * 64 * 4;      // bf16 [NN*64]
constexpr size_t OFF_VB   = OFF_KB   + (size_t)NN * 64 * 2;      // bf16 [NN*64]
constexpr size_t OFF_SRT  = OFF_VB   + (size_t)NN * 64 * 2;      // int4 [NEDGE] {src,eid,dst,0} sorted by dst
constexpr size_t OFF_Z    = OFF_SRT  + (size_t)NEDGE * 16;       // f32 [NN*8]
constexpr size_t OFF_HIST = OFF_Z    + (size_t)NN * 8 * 4;
constexpr size_t OFF_EX   = OFF_HIST + (size_t)NN * 4;
constexpr size_t OFF_BSUM = OFF_EX   + (size_t)NN * 4;
constexpr size_t OFF_BOFF = OFF_BSUM + 512 * 4;
constexpr size_t OFF_CUR  = OFF_BOFF + 512 * 4;
constexpr size_t WS_NEED  = OFF_CUR  + (size_t)NN * 4;           // ~67 MB
constexpr int NB_SCAN = (NN + 255) / 256;                         // 391

// ---------------- Q,K,V = x @ {WQ,WK,WV}; Q f32, K/V bf16 -----------------
__global__ __launch_bounds__(256) void qkv_kernel(
    const float* __restrict__ x,
    const float* __restrict__ WQ, const float* __restrict__ WK,
    const float* __restrict__ WV,
    float* __restrict__ Qf, unsigned short* __restrict__ Kb,
    unsigned short* __restrict__ Vb)
{
    const int lane = threadIdx.x & 63;
    const int wid  = threadIdx.x >> 6;
    const int gw   = blockIdx.x * 4 + wid;
    const int nw   = gridDim.x * 4;
    const int colb = lane & 15;
    const int krow = (lane >> 4) * 8;

    bf16x8 Bf[3][4][2];
    const float* Ws[3] = {WQ, WK, WV};
    #pragma unroll
    for (int m = 0; m < 3; ++m)
        #pragma unroll
        for (int n = 0; n < 4; ++n)
            #pragma unroll
            for (int kh = 0; kh < 2; ++kh) {
                bf16x8 b;
                #pragma unroll
                for (int j = 0; j < 8; ++j)
                    b[j] = f2bf(Ws[m][(size_t)(kh * 32 + krow + j) * 64 + n * 16 + colb]);
                Bf[m][n][kh] = b;
            }

    for (int tile = gw; tile < NN / 16; tile += nw) {
        const int r0 = tile * 16;
        const float* xr = x + (size_t)(r0 + colb) * 64 + krow;
        f32x4 a0 = *(const f32x4*)(xr);
        f32x4 a1 = *(const f32x4*)(xr + 4);
        f32x4 a2 = *(const f32x4*)(xr + 32);
        f32x4 a3 = *(const f32x4*)(xr + 36);
        bf16x8 Alo, Ahi;
        #pragma unroll
        for (int j = 0; j < 4; ++j) {
            Alo[j]     = f2bf(a0[j]);
            Alo[4 + j] = f2bf(a1[j]);
            Ahi[j]     = f2bf(a2[j]);
            Ahi[4 + j] = f2bf(a3[j]);
        }
        #pragma unroll
        for (int m = 0; m < 3; ++m) {
            #pragma unroll
            for (int n = 0; n < 4; ++n) {
                f32x4 acc = {0.f, 0.f, 0.f, 0.f};
                acc = __builtin_amdgcn_mfma_f32_16x16x32_bf16(Alo, Bf[m][n][0], acc, 0, 0, 0);
                acc = __builtin_amdgcn_mfma_f32_16x16x32_bf16(Ahi, Bf[m][n][1], acc, 0, 0, 0);
                #pragma unroll
                for (int q = 0; q < 4; ++q) {
                    const size_t idx = (size_t)(r0 + (lane >> 4) * 4 + q) * 64 + n * 16 + colb;
                    if (m == 0)      Qf[idx] = acc[q];
                    else if (m == 1) Kb[idx] = (unsigned short)f2bf(acc[q]);
                    else             Vb[idx] = (unsigned short)f2bf(acc[q]);
                }
            }
        }
    }
}

// ---------------- counting sort by dst -----------------------------------
__global__ void zero_hist_kernel(int* __restrict__ hist) {
    const int i = blockIdx.x * blockDim.x + threadIdx.x;
    if (i < NN) hist[i] = 0;
}

__global__ void hist_kernel(const int* __restrict__ ei, int* __restrict__ hist) {
    const int e = blockIdx.x * blockDim.x + threadIdx.x;
    if (e < NEDGE) atomicAdd(&hist[ei[NEDGE + e]], 1);
}

__global__ __launch_bounds__(256) void scanA_kernel(
    const int* __restrict__ hist, int* __restrict__ ex, int* __restrict__ bsum)
{
    __shared__ int wsum[4];
    const int i = blockIdx.x * 256 + threadIdx.x;
    const int lane = threadIdx.x & 63, wid = threadIdx.x >> 6;
    const int v = (i < NN) ? hist[i] : 0;
    int incl = v;
    #pragma unroll
    for (int off = 1; off < 64; off <<= 1) {
        int t = __shfl_up(incl, off);
        if (lane >= off) incl += t;
    }
    if (lane == 63) wsum[wid] = incl;
    __syncthreads();
    int pre = 0, bt = 0;
    #pragma unroll
    for (int w = 0; w < 4; ++w) { int s = wsum[w]; bt += s; if (w < wid) pre += s; }
    if (i < NN) ex[i] = incl - v + pre;
    if (threadIdx.x == 0) bsum[blockIdx.x] = bt;
}

__global__ __launch_bounds__(512) void scanB_kernel(
    const int* __restrict__ bsum, int* __restrict__ boff)
{
    __shared__ int wsum[8];
    const int i = threadIdx.x;
    const int lane = i & 63, wid = i >> 6;
    const int v = (i < NB_SCAN) ? bsum[i] : 0;
    int incl = v;
    #pragma unroll
    for (int off = 1; off < 64; off <<= 1) {
        int t = __shfl_up(incl, off);
        if (lane >= off) incl += t;
    }
    if (lane == 63) wsum[wid] = incl;
    __syncthreads();
    int pre = 0;
    #pragma unroll
    for (int w = 0; w < 8; ++w) { if (w < wid) pre += wsum[w]; }
    if (i < NB_SCAN) boff[i] = incl - v + pre;
}

__global__ void scanC_kernel(const int* __restrict__ ex, const int* __restrict__ boff,
                             int* __restrict__ cursor)
{
    const int i = blockIdx.x * blockDim.x + threadIdx.x;
    if (i < NN) cursor[i] = ex[i] + boff[i >> 8];
}

__global__ void scatter_kernel(const int* __restrict__ ei, int* __restrict__ cursor,
                               int4* __restrict__ sorted4)
{
    const int e = blockIdx.x * blockDim.x + threadIdx.x;
    if (e < NEDGE) {
        const int dst = ei[NEDGE + e];
        const int pos = atomicAdd(&cursor[dst], 1);
        sorted4[pos] = make_int4(ei[e], e, dst, 0);
    }
}

// ---------------- zero accumulators ---------------------------------------
__global__ void zero_outz_kernel(float* __restrict__ out, float* __restrict__ Z) {
    const int i = blockIdx.x * blockDim.x + threadIdx.x;
    if (i < NN * 64) out[i] = 0.f;
    if (i < NN * 8)  Z[i]   = 0.f;
}

// ---------------- windowed fused aggregation ------------------------------
// One wave per 16-edge window of the dst-sorted edge list (static mapping,
// no padding, perfectly balanced). Phase A: MFMA Ef of the 16 edges (LDS
// transpose). Phase B: per-(edge,head) score + msg. Segment loop over the
// <=16 dst-runs: masked xor-reduce over edge slots + fp32 atomics into
// out/Z accumulators. Next window's sorted4/edge_attr prefetched depth-1.
__global__ __launch_bounds__(256) void agg_kernel(
    const float* __restrict__ Qn, const unsigned short* __restrict__ Kb,
    const unsigned short* __restrict__ Vb,
    const float* __restrict__ edge_attr, const float* __restrict__ WE,
    const int4* __restrict__ sorted4,
    float* __restrict__ outAcc, float* __restrict__ Z)
{
    const int lane = threadIdx.x & 63;
    const int wid  = threadIdx.x >> 6;
    const int gw   = (blockIdx.x * blockDim.x + threadIdx.x) >> 6;
    const int nw   = (gridDim.x * blockDim.x) >> 6;
    const int colb = lane & 15;
    const int krow = (lane >> 4) * 8;
    const int el   = lane >> 3;     // edge slot 0..7
    const int h    = lane & 7;      // head 0..7
    const float c  = 0.35355339059327373f;   // 1/sqrt(8)

    __shared__ float efs_all[4][16][68];
    float (*efs)[68] = efs_all[wid];

    // WE fragments: 4 col-tiles x 2 k-halves (32 VGPRs)
    bf16x8 Bf[4][2];
    #pragma unroll
    for (int n = 0; n < 4; ++n)
        #pragma unroll
        for (int kh = 0; kh < 2; ++kh) {
            bf16x8 b;
            #pragma unroll
            for (int j = 0; j < 8; ++j)
                b[j] = f2bf(WE[(size_t)(kh * 32 + krow + j) * 64 + n * 16 + colb]);
            Bf[n][kh] = b;
        }

    int w = gw;
    int4 se = make_int4(0, 0, 0, 0);
    f32x4 a0 = {0,0,0,0}, a1 = {0,0,0,0}, a2 = {0,0,0,0}, a3 = {0,0,0,0};
    if (w < NW) {
        se = sorted4[(size_t)w * 16 + colb];       // every lane: edge (lane&15)
        const float* ear = edge_attr + (size_t)se.y * 64 + krow;
        a0 = *(const f32x4*)(ear);
        a1 = *(const f32x4*)(ear + 4);
        a2 = *(const f32x4*)(ear + 32);
        a3 = *(const f32x4*)(ear + 36);
    }

    for (; w < NW; w += nw) {
        const int wn = w + nw;
        int4 se_n = make_int4(0, 0, 0, 0);
        if (wn < NW) se_n = sorted4[(size_t)wn * 16 + colb];

        // per-edge endpoints for phase B (bpermute from lanes 0..15)
        const int s0 = __shfl(se.x, el);
        const int s1 = __shfl(se.x, el + 8);
        const int d0 = __shfl(se.z, el);
        const int d1 = __shfl(se.z, el + 8);

        // segment-start mask (dst runs within the window; dsts sorted)
        const int prevd = __shfl(se.z, (colb == 0) ? 0 : colb - 1);
        const bool isS = (lane < 16) && (lane == 0 || prevd != se.z);
        const unsigned segmask = (unsigned)(__ballot(isS) & 0xFFFFull);

        // issue K/V/Q gathers early (independent of MFMA)
        const u16x8 k0v = *(const u16x8*)(Kb + (size_t)s0 * 64 + h * 8);
        const u16x8 v0v = *(const u16x8*)(Vb + (size_t)s0 * 64 + h * 8);
        const u16x8 k1v = *(const u16x8*)(Kb + (size_t)s1 * 64 + h * 8);
        const u16x8 v1v = *(const u16x8*)(Vb + (size_t)s1 * 64 + h * 8);
        const float* qp0 = Qn + (size_t)d0 * 64 + h * 8;
        const f32x4 q00 = *(const f32x4*)(qp0);
        const f32x4 q01 = *(const f32x4*)(qp0 + 4);
        const float* qp1 = Qn + (size_t)d1 * 64 + h * 8;
        const f32x4 q10 = *(const f32x4*)(qp1);
        const f32x4 q11 = *(const f32x4*)(qp1 + 4);

        // phase A: pack + MFMA -> efs
        bf16x8 Alo, Ahi;
        #pragma unroll
        for (int jj = 0; jj < 4; ++jj) {
            Alo[jj]     = f2bf(a0[jj]);
            Alo[4 + jj] = f2bf(a1[jj]);
            Ahi[jj]     = f2bf(a2[jj]);
            Ahi[4 + jj] = f2bf(a3[jj]);
        }
        const int rbase = (lane >> 4) * 4;
        #pragma unroll
        for (int n = 0; n < 4; ++n) {
            f32x4 z = {0.f, 0.f, 0.f, 0.f};
            z = __builtin_amdgcn_mfma_f32_16x16x32_bf16(Alo, Bf[n][0], z, 0, 0, 0);
            z = __builtin_amdgcn_mfma_f32_16x16x32_bf16(Ahi, Bf[n][1], z, 0, 0, 0);
            #pragma unroll
            for (int q = 0; q < 4; ++q)
                efs[rbase + q][n * 16 + colb] = z[q];
        }

        // prefetch next window's edge_attr (depth-1 pipeline)
        f32x4 a0n = {0,0,0,0}, a1n = {0,0,0,0}, a2n = {0,0,0,0}, a3n = {0,0,0,0};
        if (wn < NW) {
            const float* earn = edge_attr + (size_t)se_n.y * 64 + krow;
            a0n = *(const f32x4*)(earn);
            a1n = *(const f32x4*)(earn + 4);
            a2n = *(const f32x4*)(earn + 32);
            a3n = *(const f32x4*)(earn + 36);
        }

        // wave-private LDS; DS pipe in-order per wave
        asm volatile("s_waitcnt lgkmcnt(0)" ::: "memory");
        __builtin_amdgcn_sched_barrier(0);

        // phase B: scores + messages (no padding — all 16 edges real)
        const f32x4 e00 = *(const f32x4*)(&efs[el][h * 8]);
        const f32x4 e01 = *(const f32x4*)(&efs[el][h * 8 + 4]);
        const f32x4 e10 = *(const f32x4*)(&efs[el + 8][h * 8]);
        const f32x4 e11 = *(const f32x4*)(&efs[el + 8][h * 8 + 4]);
        float t0 = 0.f, t1 = 0.f;
        #pragma unroll
        for (int d = 0; d < 4; ++d) {
            t0 += bf2f(k0v[d])     * q00[d] * e00[d];
            t0 += bf2f(k0v[4 + d]) * q01[d] * e01[d];
            t1 += bf2f(k1v[d])     * q10[d] * e10[d];
            t1 += bf2f(k1v[4 + d]) * q11[d] * e11[d];
        }
        const float sc0 = __expf(fminf(fmaxf(t0 * c, -5.f), 5.f));
        const float sc1 = __expf(fminf(fmaxf(t1 * c, -5.f), 5.f));
        f32x4 m00, m01, m10, m11;
        #pragma unroll
        for (int d = 0; d < 4; ++d) {
            m00[d] = bf2f(v0v[d])     * sc0;
            m01[d] = bf2f(v0v[4 + d]) * sc0;
            m10[d] = bf2f(v1v[d])     * sc1;
            m11[d] = bf2f(v1v[4 + d]) * sc1;
        }

        // segment loop: one iteration per dst-run (wave-uniform mask)
        unsigned mask = segmask;
        while (mask) {
            const int i = __builtin_ctz(mask);
            const unsigned rest = mask & (mask - 1u);
            const int jend = rest ? __builtin_ctz(rest) : 16;
            mask = rest;
            const int cur = __shfl(se.z, i);
            const bool act0 = (el >= i) && (el < jend);
            const bool act1 = (el + 8 >= i) && (el + 8 < jend);
            float sz = (act0 ? sc0 : 0.f) + (act1 ? sc1 : 0.f);
            f32x4 sm0, sm1;
            #pragma unroll
            for (int d = 0; d < 4; ++d) {
                sm0[d] = (act0 ? m00[d] : 0.f) + (act1 ? m10[d] : 0.f);
                sm1[d] = (act0 ? m01[d] : 0.f) + (act1 ? m11[d] : 0.f);
            }
            #pragma unroll
            for (int off = 8; off < 64; off <<= 1) {
                sz += __shfl_xor(sz, off);
                #pragma unroll
                for (int d = 0; d < 4; ++d) {
                    sm0[d] += __shfl_xor(sm0[d], off);
                    sm1[d] += __shfl_xor(sm1[d], off);
                }
            }
            if (el == 0) {
                float* op = outAcc + (size_t)cur * 64 + h * 8;
                #pragma unroll
                for (int d = 0; d < 4; ++d) {
                    unsafeAtomicAdd(op + d,     sm0[d]);
                    unsafeAtomicAdd(op + 4 + d, sm1[d]);
                }
                unsafeAtomicAdd(&Z[(size_t)cur * 8 + h], sz);
            }
        }

        // rotate pipeline
        se = se_n;
        a0 = a0n; a1 = a1n; a2 = a2n; a3 = a3n;
    }
}

// ---------------- finalize: out = acc / (Z + 1e-6) ------------------------
__global__ void finalize_kernel(float* __restrict__ out, const float* __restrict__ Z) {
    const int i = blockIdx.x * blockDim.x + threadIdx.x;
    if (i < NN * 64) {
        const int node = i >> 6;
        const int h    = (i >> 3) & 7;
        out[i] = out[i] / (Z[node * 8 + h] + 1e-6f);
    }
}

// ---------------- fallback path (atomic, small ws) ------------------------
__global__ __launch_bounds__(256) void edge_kernel_fb(
    const float* __restrict__ edge_attr, const float* __restrict__ WE,
    const float* __restrict__ Qn, const unsigned short* __restrict__ Kb,
    const unsigned short* __restrict__ Vb, const int* __restrict__ ei,
    float* __restrict__ outAcc, float* __restrict__ Z)
{
    const int lane = threadIdx.x & 63;
    const int wid  = threadIdx.x >> 6;
    const int gw   = blockIdx.x * 4 + wid;
    const int nw   = gridDim.x * 4;
    const int colb = lane & 15;
    const int krow = (lane >> 4) * 8;
    const int b8   = (lane >> 3) & 1;

    bf16x8 Bf[4][2];
    #pragma unroll
    for (int n = 0; n < 4; ++n)
        #pragma unroll
        for (int kh = 0; kh < 2; ++kh) {
            bf16x8 b;
            #pragma unroll
            for (int j = 0; j < 8; ++j)
                b[j] = f2bf(WE[(size_t)(kh * 32 + krow + j) * 64 + n * 16 + colb]);
            Bf[n][kh] = b;
        }

    const float inv_sqrt_dh = 0.35355339059327373f;

    for (int tile = gw; tile < NEDGE / 16; tile += nw) {
        const int e0 = tile * 16;
        const float* ear = edge_attr + (size_t)(e0 + colb) * 64 + krow;
        f32x4 a0 = *(const f32x4*)(ear);
        f32x4 a1 = *(const f32x4*)(ear + 4);
        f32x4 a2 = *(const f32x4*)(ear + 32);
        f32x4 a3 = *(const f32x4*)(ear + 36);
        bf16x8 Alo, Ahi;
        #pragma unroll
        for (int j = 0; j < 4; ++j) {
            Alo[j]     = f2bf(a0[j]);
            Alo[4 + j] = f2bf(a1[j]);
            Ahi[j]     = f2bf(a2[j]);
            Ahi[4 + j] = f2bf(a3[j]);
        }
        f32x4 acc[4];
        #pragma unroll
        for (int n = 0; n < 4; ++n) {
            f32x4 z = {0.f, 0.f, 0.f, 0.f};
            z = __builtin_amdgcn_mfma_f32_16x16x32_bf16(Alo, Bf[n][0], z, 0, 0, 0);
            z = __builtin_amdgcn_mfma_f32_16x16x32_bf16(Ahi, Bf[n][1], z, 0, 0, 0);
            acc[n] = z;
        }
        int srcq[4], dstq[4];
        #pragma unroll
        for (int q = 0; q < 4; ++q) {
            const int erl = (lane >> 4) * 4 + q;
            srcq[q] = ei[e0 + erl];
            dstq[q] = ei[NEDGE + e0 + erl];
        }
        float sc[4][4];
        #pragma unroll
        for (int q = 0; q < 4; ++q) {
            #pragma unroll
            for (int n = 0; n < 4; ++n) {
                const int cidx = n * 16 + colb;
                const float kv = bf2f(Kb[(size_t)srcq[q] * 64 + cidx]);
                const float qv = Qn[(size_t)dstq[q] * 64 + cidx];
                float t = kv * qv * acc[n][q];
                t += __shfl_xor(t, 1);
                t += __shfl_xor(t, 2);
                t += __shfl_xor(t, 4);
                const float s = fminf(fmaxf(t * inv_sqrt_dh, -5.0f), 5.0f);
                sc[q][n] = __expf(s);
            }
        }
        #pragma unroll
        for (int q = 0; q < 4; ++q) {
            #pragma unroll
            for (int n = 0; n < 4; ++n) {
                const int cidx = n * 16 + colb;
                const float vv = bf2f(Vb[(size_t)srcq[q] * 64 + cidx]);
                unsafeAtomicAdd(&outAcc[(size_t)dstq[q] * 64 + cidx], vv * sc[q][n]);
                if ((lane & 7) == 0) {
                    const int hh = 2 * n + b8;
                    unsafeAtomicAdd(&Z[(size_t)dstq[q] * 8 + hh], sc[q][n]);
                }
            }
        }
    }
}

extern "C" void kernel_launch(void* const* d_in, const int* in_sizes, int n_in,
                              void* d_out, int out_size, void* d_ws, size_t ws_size,
                              hipStream_t stream) {
    const float* x         = (const float*)d_in[0];
    const float* edge_attr = (const float*)d_in[1];
    const float* WQ        = (const float*)d_in[2];
    const float* WK        = (const float*)d_in[3];
    const float* WV        = (const float*)d_in[4];
    const float* WE        = (const float*)d_in[5];
    const int*   ei        = (const int*)d_in[6];
    float* out = (float*)d_out;

    char* base = (char*)d_ws;
    float*          Qf = (float*)(base + OFF_Q);
    unsigned short* Kb = (unsigned short*)(base + OFF_KB);
    unsigned short* Vb = (unsigned short*)(base + OFF_VB);

    qkv_kernel<<<1563, 256, 0, stream>>>(x, WQ, WK, WV, Qf, Kb, Vb);

    if (ws_size >= WS_NEED) {
        int4* sorted4 = (int4*)(base + OFF_SRT);
        float* Z      = (float*)(base + OFF_Z);
        int* hist     = (int*)(base + OFF_HIST);
        int* ex       = (int*)(base + OFF_EX);
        int* bsum     = (int*)(base + OFF_BSUM);
        int* boff     = (int*)(base + OFF_BOFF);
        int* cursor   = (int*)(base + OFF_CUR);

        zero_hist_kernel<<<NB_SCAN, 256, 0, stream>>>(hist);
        hist_kernel<<<(NEDGE + 255) / 256, 256, 0, stream>>>(ei, hist);
        scanA_kernel<<<NB_SCAN, 256, 0, stream>>>(hist, ex, bsum);
        scanB_kernel<<<1, 512, 0, stream>>>(bsum, boff);
        scanC_kernel<<<NB_SCAN, 256, 0, stream>>>(ex, boff, cursor);
        scatter_kernel<<<(NEDGE + 255) / 256, 256, 0, stream>>>(ei, cursor, sorted4);
        zero_outz_kernel<<<(NN * 64 + 255) / 256, 256, 0, stream>>>(out, Z);
        agg_kernel<<<4096, 256, 0, stream>>>(Qf, Kb, Vb, edge_attr, WE, sorted4, out, Z);
        finalize_kernel<<<(NN * 64 + 255) / 256, 256, 0, stream>>>(out, Z);
    } else {
        // fallback: atomic path
        float* Z = (float*)(base + OFF_SRT);
        hipMemsetAsync(d_out, 0, (size_t)NN * 64 * sizeof(float), stream);
        hipMemsetAsync(Z, 0, (size_t)NN * 8 * sizeof(float), stream);
        edge_kernel_fb<<<2048, 256, 0, stream>>>(edge_attr, WE, Qf, Kb, Vb, ei, out, Z);
        finalize_kernel<<<(NN * 64 + 255) / 256, 256, 0, stream>>>(out, Z);
    }
}

// Round 9
// 319.285 us; speedup vs baseline: 1.8189x; 1.8189x over previous
//
#include <hip/hip_runtime.h>
#include <hip/hip_bf16.h>

#define NN    100000
#define NEDGE 1250000

typedef __attribute__((ext_vector_type(8))) short bf16x8;
typedef __attribute__((ext_vector_type(8))) unsigned short u16x8;
typedef __attribute__((ext_vector_type(4))) float f32x4;

__device__ __forceinline__ short f2bf(float f) {
    unsigned u = __float_as_uint(f);
    u += 0x7FFFu + ((u >> 16) & 1u);   // round-to-nearest-even
    return (short)(u >> 16);
}
__device__ __forceinline__ float bf2f(unsigned short u) {
    return __uint_as_float(((unsigned)u) << 16);
}

// ws layout (bytes)
constexpr size_t OFF_Q    = 0;                                   // f32 [NN*64]
constexpr size_t OFF_KB   = OFF_Q    + (size_t)NN * 64 * 4;      // bf16 [NN*64]
constexpr size_t OFF_VB   = OFF_KB   + (size_t)NN * 64 * 2;      // bf16 [NN*64]
constexpr size_t OFF_SRT  = OFF_VB   + (size_t)NN * 64 * 2;      // int2 [NEDGE] {src, eid} sorted by dst
constexpr size_t OFF_HIST = OFF_SRT  + (size_t)NEDGE * 8;
constexpr size_t OFF_EX   = OFF_HIST + (size_t)NN * 4;
constexpr size_t OFF_BSUM = OFF_EX   + (size_t)NN * 4;
constexpr size_t OFF_BOFF = OFF_BSUM + 512 * 4;
constexpr size_t OFF_START= OFF_BOFF + 512 * 4;
constexpr size_t OFF_CUR  = OFF_START+ (size_t)(NN + 1) * 4;
constexpr size_t WS_NEED  = OFF_CUR  + (size_t)NN * 4;           // ~63 MB
constexpr int NB_SCAN = (NN + 255) / 256;                         // 391

// ---------------- Q,K,V = x @ {WQ,WK,WV}; Q f32, K/V bf16 -----------------
__global__ __launch_bounds__(256) void qkv_kernel(
    const float* __restrict__ x,
    const float* __restrict__ WQ, const float* __restrict__ WK,
    const float* __restrict__ WV,
    float* __restrict__ Qf, unsigned short* __restrict__ Kb,
    unsigned short* __restrict__ Vb)
{
    const int lane = threadIdx.x & 63;
    const int wid  = threadIdx.x >> 6;
    const int gw   = blockIdx.x * 4 + wid;
    const int nw   = gridDim.x * 4;
    const int colb = lane & 15;
    const int krow = (lane >> 4) * 8;

    bf16x8 Bf[3][4][2];
    const float* Ws[3] = {WQ, WK, WV};
    #pragma unroll
    for (int m = 0; m < 3; ++m)
        #pragma unroll
        for (int n = 0; n < 4; ++n)
            #pragma unroll
            for (int kh = 0; kh < 2; ++kh) {
                bf16x8 b;
                #pragma unroll
                for (int j = 0; j < 8; ++j)
                    b[j] = f2bf(Ws[m][(size_t)(kh * 32 + krow + j) * 64 + n * 16 + colb]);
                Bf[m][n][kh] = b;
            }

    for (int tile = gw; tile < NN / 16; tile += nw) {
        const int r0 = tile * 16;
        const float* xr = x + (size_t)(r0 + colb) * 64 + krow;
        f32x4 a0 = *(const f32x4*)(xr);
        f32x4 a1 = *(const f32x4*)(xr + 4);
        f32x4 a2 = *(const f32x4*)(xr + 32);
        f32x4 a3 = *(const f32x4*)(xr + 36);
        bf16x8 Alo, Ahi;
        #pragma unroll
        for (int j = 0; j < 4; ++j) {
            Alo[j]     = f2bf(a0[j]);
            Alo[4 + j] = f2bf(a1[j]);
            Ahi[j]     = f2bf(a2[j]);
            Ahi[4 + j] = f2bf(a3[j]);
        }
        #pragma unroll
        for (int m = 0; m < 3; ++m) {
            #pragma unroll
            for (int n = 0; n < 4; ++n) {
                f32x4 acc = {0.f, 0.f, 0.f, 0.f};
                acc = __builtin_amdgcn_mfma_f32_16x16x32_bf16(Alo, Bf[m][n][0], acc, 0, 0, 0);
                acc = __builtin_amdgcn_mfma_f32_16x16x32_bf16(Ahi, Bf[m][n][1], acc, 0, 0, 0);
                #pragma unroll
                for (int q = 0; q < 4; ++q) {
                    const size_t idx = (size_t)(r0 + (lane >> 4) * 4 + q) * 64 + n * 16 + colb;
                    if (m == 0)      Qf[idx] = acc[q];
                    else if (m == 1) Kb[idx] = (unsigned short)f2bf(acc[q]);
                    else             Vb[idx] = (unsigned short)f2bf(acc[q]);
                }
            }
        }
    }
}

// ---------------- counting sort by dst -----------------------------------
__global__ void zero_hist_kernel(int* __restrict__ hist) {
    const int i = blockIdx.x * blockDim.x + threadIdx.x;
    if (i < NN) hist[i] = 0;
}

__global__ void hist_kernel(const int* __restrict__ ei, int* __restrict__ hist) {
    const int e = blockIdx.x * blockDim.x + threadIdx.x;
    if (e < NEDGE) atomicAdd(&hist[ei[NEDGE + e]], 1);
}

__global__ __launch_bounds__(256) void scanA_kernel(
    const int* __restrict__ hist, int* __restrict__ ex, int* __restrict__ bsum)
{
    __shared__ int wsum[4];
    const int i = blockIdx.x * 256 + threadIdx.x;
    const int lane = threadIdx.x & 63, wid = threadIdx.x >> 6;
    const int v = (i < NN) ? hist[i] : 0;
    int incl = v;
    #pragma unroll
    for (int off = 1; off < 64; off <<= 1) {
        int t = __shfl_up(incl, off);
        if (lane >= off) incl += t;
    }
    if (lane == 63) wsum[wid] = incl;
    __syncthreads();
    int pre = 0, bt = 0;
    #pragma unroll
    for (int w = 0; w < 4; ++w) { int s = wsum[w]; bt += s; if (w < wid) pre += s; }
    if (i < NN) ex[i] = incl - v + pre;
    if (threadIdx.x == 0) bsum[blockIdx.x] = bt;
}

__global__ __launch_bounds__(512) void scanB_kernel(
    const int* __restrict__ bsum, int* __restrict__ boff)
{
    __shared__ int wsum[8];
    const int i = threadIdx.x;
    const int lane = i & 63, wid = i >> 6;
    const int v = (i < NB_SCAN) ? bsum[i] : 0;
    int incl = v;
    #pragma unroll
    for (int off = 1; off < 64; off <<= 1) {
        int t = __shfl_up(incl, off);
        if (lane >= off) incl += t;
    }
    if (lane == 63) wsum[wid] = incl;
    __syncthreads();
    int pre = 0;
    #pragma unroll
    for (int w = 0; w < 8; ++w) { if (w < wid) pre += wsum[w]; }
    if (i < NB_SCAN) boff[i] = incl - v + pre;
}

__global__ void scanC_kernel(const int* __restrict__ ex, const int* __restrict__ boff,
                             int* __restrict__ start, int* __restrict__ cursor)
{
    const int i = blockIdx.x * blockDim.x + threadIdx.x;
    if (i < NN) {
        const int s = ex[i] + boff[i >> 8];
        start[i] = s;
        cursor[i] = s;
    } else if (i == NN) {
        start[NN] = NEDGE;
    }
}

__global__ void scatter_kernel(const int* __restrict__ ei, int* __restrict__ cursor,
                               int2* __restrict__ sorted)
{
    const int e = blockIdx.x * blockDim.x + threadIdx.x;
    if (e < NEDGE) {
        const int dst = ei[NEDGE + e];
        const int pos = atomicAdd(&cursor[dst], 1);
        sorted[pos] = make_int2(ei[e], e);
    }
}

// ---------------- fused aggregation, depth-1 pipelined across dsts --------
// One wave per dst (round-7 structure). Next dst (dst+nw, statically known)
// has its start/sorted/edge_attr chain issued under the current dst's
// MFMA + score work. Current K/V/Q gathers issued before MFMA.
__global__ __launch_bounds__(256) void agg_kernel(
    const float* __restrict__ Qn, const unsigned short* __restrict__ Kb,
    const unsigned short* __restrict__ Vb,
    const float* __restrict__ edge_attr, const float* __restrict__ WE,
    const int* __restrict__ start, const int2* __restrict__ sorted,
    float* __restrict__ out)
{
    const int lane = threadIdx.x & 63;
    const int wid  = threadIdx.x >> 6;
    const int gw   = (blockIdx.x * blockDim.x + threadIdx.x) >> 6;
    const int nw   = (gridDim.x * blockDim.x) >> 6;
    const int colb = lane & 15;
    const int krow = (lane >> 4) * 8;
    const int el   = lane >> 3;     // edge slot 0..7
    const int h    = lane & 7;      // head 0..7
    const float c  = 0.35355339059327373f;   // 1/sqrt(8)

    __shared__ float efs_all[4][16][68];
    float (*efs)[68] = efs_all[wid];

    // WE fragments: 4 col-tiles x 2 k-halves (32 VGPRs)
    bf16x8 Bf[4][2];
    #pragma unroll
    for (int n = 0; n < 4; ++n)
        #pragma unroll
        for (int kh = 0; kh < 2; ++kh) {
            bf16x8 b;
            #pragma unroll
            for (int j = 0; j < 8; ++j)
                b[j] = f2bf(WE[(size_t)(kh * 32 + krow + j) * 64 + n * 16 + colb]);
            Bf[n][kh] = b;
        }

    // prologue: load first dst's state
    int dst = gw;
    int beg = 0, end = 0;
    int2 se = make_int2(0, 0);
    f32x4 a0 = {0,0,0,0}, a1 = {0,0,0,0}, a2 = {0,0,0,0}, a3 = {0,0,0,0};
    if (dst < NN) {
        beg = start[dst]; end = start[dst + 1];
        int rpos = beg + colb;
        if (rpos >= end) rpos = beg;
        if (rpos >= NEDGE) rpos = NEDGE - 1;
        se = sorted[rpos];
        const float* ear = edge_attr + (size_t)se.y * 64 + krow;
        a0 = *(const f32x4*)(ear);
        a1 = *(const f32x4*)(ear + 4);
        a2 = *(const f32x4*)(ear + 32);
        a3 = *(const f32x4*)(ear + 36);
    }

    for (; dst < NN; dst += nw) {
        const int dn = dst + nw;
        // next-dst start[] issued first (latency hidden under everything below)
        int beg_n = 0, end_n = 0;
        if (dn < NN) { beg_n = start[dn]; end_n = start[dn + 1]; }

        // current-dst K/V/Q gathers, independent of MFMA — issue early
        const int s0 = __shfl(se.x, el);
        const int s1 = __shfl(se.x, el + 8);
        const u16x8 k0v = *(const u16x8*)(Kb + (size_t)s0 * 64 + h * 8);
        const u16x8 v0v = *(const u16x8*)(Vb + (size_t)s0 * 64 + h * 8);
        const u16x8 k1v = *(const u16x8*)(Kb + (size_t)s1 * 64 + h * 8);
        const u16x8 v1v = *(const u16x8*)(Vb + (size_t)s1 * 64 + h * 8);
        const float* qp = Qn + (size_t)dst * 64 + h * 8;
        const f32x4 q0 = *(const f32x4*)(qp);
        const f32x4 q1 = *(const f32x4*)(qp + 4);

        // phase A: pack + MFMA -> efs (first 16-edge batch)
        bf16x8 Alo, Ahi;
        #pragma unroll
        for (int jj = 0; jj < 4; ++jj) {
            Alo[jj]     = f2bf(a0[jj]);
            Alo[4 + jj] = f2bf(a1[jj]);
            Ahi[jj]     = f2bf(a2[jj]);
            Ahi[4 + jj] = f2bf(a3[jj]);
        }
        const int rbase = (lane >> 4) * 4;
        #pragma unroll
        for (int n = 0; n < 4; ++n) {
            f32x4 z = {0.f, 0.f, 0.f, 0.f};
            z = __builtin_amdgcn_mfma_f32_16x16x32_bf16(Alo, Bf[n][0], z, 0, 0, 0);
            z = __builtin_amdgcn_mfma_f32_16x16x32_bf16(Ahi, Bf[n][1], z, 0, 0, 0);
            #pragma unroll
            for (int q = 0; q < 4; ++q)
                efs[rbase + q][n * 16 + colb] = z[q];
        }

        // next-dst dependent chain: sorted -> edge_attr (hidden under phase B)
        int2 se_n = make_int2(0, 0);
        f32x4 a0n = {0,0,0,0}, a1n = {0,0,0,0}, a2n = {0,0,0,0}, a3n = {0,0,0,0};
        if (dn < NN) {
            int rpos_n = beg_n + colb;
            if (rpos_n >= end_n) rpos_n = beg_n;
            if (rpos_n >= NEDGE) rpos_n = NEDGE - 1;
            se_n = sorted[rpos_n];
            const float* earn = edge_attr + (size_t)se_n.y * 64 + krow;
            a0n = *(const f32x4*)(earn);
            a1n = *(const f32x4*)(earn + 4);
            a2n = *(const f32x4*)(earn + 32);
            a3n = *(const f32x4*)(earn + 36);
        }

        // wave-private LDS; DS pipe in-order per wave
        asm volatile("s_waitcnt lgkmcnt(0)" ::: "memory");
        __builtin_amdgcn_sched_barrier(0);

        // phase B: first batch scores + accumulate
        f32x4 av0 = {0,0,0,0}, av1 = {0,0,0,0};
        float az = 0.f;
        {
            const f32x4 e00 = *(const f32x4*)(&efs[el][h * 8]);
            const f32x4 e01 = *(const f32x4*)(&efs[el][h * 8 + 4]);
            const f32x4 e10 = *(const f32x4*)(&efs[el + 8][h * 8]);
            const f32x4 e11 = *(const f32x4*)(&efs[el + 8][h * 8 + 4]);
            float t0 = 0.f, t1 = 0.f;
            #pragma unroll
            for (int d = 0; d < 4; ++d) {
                t0 += bf2f(k0v[d])     * q0[d] * e00[d];
                t0 += bf2f(k0v[4 + d]) * q1[d] * e01[d];
                t1 += bf2f(k1v[d])     * q0[d] * e10[d];
                t1 += bf2f(k1v[4 + d]) * q1[d] * e11[d];
            }
            const bool act0 = (beg + el)     < end;
            const bool act1 = (beg + el + 8) < end;
            const float sc0 = act0 ? __expf(fminf(fmaxf(t0 * c, -5.f), 5.f)) : 0.f;
            const float sc1 = act1 ? __expf(fminf(fmaxf(t1 * c, -5.f), 5.f)) : 0.f;
            az += sc0 + sc1;
            #pragma unroll
            for (int d = 0; d < 4; ++d) {
                av0[d] += bf2f(v0v[d])     * sc0 + bf2f(v1v[d])     * sc1;
                av1[d] += bf2f(v0v[4 + d]) * sc0 + bf2f(v1v[4 + d]) * sc1;
            }
        }

        // extra batches (deg > 16, ~13% of dsts): serial path
        for (int j = beg + 16; j < end; j += 16) {
            int rpos = j + colb;
            if (rpos >= end) rpos = beg;
            const int2 seb = sorted[rpos];
            const int sb0 = __shfl(seb.x, el);
            const int sb1 = __shfl(seb.x, el + 8);
            const u16x8 kb0 = *(const u16x8*)(Kb + (size_t)sb0 * 64 + h * 8);
            const u16x8 vb0 = *(const u16x8*)(Vb + (size_t)sb0 * 64 + h * 8);
            const u16x8 kb1 = *(const u16x8*)(Kb + (size_t)sb1 * 64 + h * 8);
            const u16x8 vb1 = *(const u16x8*)(Vb + (size_t)sb1 * 64 + h * 8);
            const float* earb = edge_attr + (size_t)seb.y * 64 + krow;
            const f32x4 b0 = *(const f32x4*)(earb);
            const f32x4 b1 = *(const f32x4*)(earb + 4);
            const f32x4 b2 = *(const f32x4*)(earb + 32);
            const f32x4 b3 = *(const f32x4*)(earb + 36);
            bf16x8 Blo, Bhi;
            #pragma unroll
            for (int jj = 0; jj < 4; ++jj) {
                Blo[jj]     = f2bf(b0[jj]);
                Blo[4 + jj] = f2bf(b1[jj]);
                Bhi[jj]     = f2bf(b2[jj]);
                Bhi[4 + jj] = f2bf(b3[jj]);
            }
            #pragma unroll
            for (int n = 0; n < 4; ++n) {
                f32x4 z = {0.f, 0.f, 0.f, 0.f};
                z = __builtin_amdgcn_mfma_f32_16x16x32_bf16(Blo, Bf[n][0], z, 0, 0, 0);
                z = __builtin_amdgcn_mfma_f32_16x16x32_bf16(Bhi, Bf[n][1], z, 0, 0, 0);
                #pragma unroll
                for (int q = 0; q < 4; ++q)
                    efs[rbase + q][n * 16 + colb] = z[q];
            }
            asm volatile("s_waitcnt lgkmcnt(0)" ::: "memory");
            __builtin_amdgcn_sched_barrier(0);
            const f32x4 e00 = *(const f32x4*)(&efs[el][h * 8]);
            const f32x4 e01 = *(const f32x4*)(&efs[el][h * 8 + 4]);
            const f32x4 e10 = *(const f32x4*)(&efs[el + 8][h * 8]);
            const f32x4 e11 = *(const f32x4*)(&efs[el + 8][h * 8 + 4]);
            float t0 = 0.f, t1 = 0.f;
            #pragma unroll
            for (int d = 0; d < 4; ++d) {
                t0 += bf2f(kb0[d])     * q0[d] * e00[d];
                t0 += bf2f(kb0[4 + d]) * q1[d] * e01[d];
                t1 += bf2f(kb1[d])     * q0[d] * e10[d];
                t1 += bf2f(kb1[4 + d]) * q1[d] * e11[d];
            }
            const bool act0 = (j + el)     < end;
            const bool act1 = (j + el + 8) < end;
            const float sc0 = act0 ? __expf(fminf(fmaxf(t0 * c, -5.f), 5.f)) : 0.f;
            const float sc1 = act1 ? __expf(fminf(fmaxf(t1 * c, -5.f), 5.f)) : 0.f;
            az += sc0 + sc1;
            #pragma unroll
            for (int d = 0; d < 4; ++d) {
                av0[d] += bf2f(vb0[d])     * sc0 + bf2f(vb1[d])     * sc1;
                av1[d] += bf2f(vb0[4 + d]) * sc0 + bf2f(vb1[4 + d]) * sc1;
            }
        }

        // reduce across the 8 edge slots for each head
        #pragma unroll
        for (int off = 8; off < 64; off <<= 1) {
            az += __shfl_xor(az, off);
            #pragma unroll
            for (int d = 0; d < 4; ++d) {
                av0[d] += __shfl_xor(av0[d], off);
                av1[d] += __shfl_xor(av1[d], off);
            }
        }

        if (el == 0) {
            const float inv = 1.f / (az + 1e-6f);
            f32x4 o0, o1;
            #pragma unroll
            for (int d = 0; d < 4; ++d) { o0[d] = av0[d] * inv; o1[d] = av1[d] * inv; }
            float* op = out + (size_t)dst * 64 + h * 8;
            *(f32x4*)(op)     = o0;
            *(f32x4*)(op + 4) = o1;
        }

        // rotate pipeline
        beg = beg_n; end = end_n; se = se_n;
        a0 = a0n; a1 = a1n; a2 = a2n; a3 = a3n;
    }
}

// ---------------- fallback path (atomic, small ws) ------------------------
__global__ __launch_bounds__(256) void edge_kernel_fb(
    const float* __restrict__ edge_attr, const float* __restrict__ WE,
    const float* __restrict__ Qn, const unsigned short* __restrict__ Kb,
    const unsigned short* __restrict__ Vb, const int* __restrict__ ei,
    float* __restrict__ outAcc, float* __restrict__ Z)
{
    const int lane = threadIdx.x & 63;
    const int wid  = threadIdx.x >> 6;
    const int gw   = blockIdx.x * 4 + wid;
    const int nw   = gridDim.x * 4;
    const int colb = lane & 15;
    const int krow = (lane >> 4) * 8;
    const int b8   = (lane >> 3) & 1;

    bf16x8 Bf[4][2];
    #pragma unroll
    for (int n = 0; n < 4; ++n)
        #pragma unroll
        for (int kh = 0; kh < 2; ++kh) {
            bf16x8 b;
            #pragma unroll
            for (int j = 0; j < 8; ++j)
                b[j] = f2bf(WE[(size_t)(kh * 32 + krow + j) * 64 + n * 16 + colb]);
            Bf[n][kh] = b;
        }

    const float inv_sqrt_dh = 0.35355339059327373f;

    for (int tile = gw; tile < NEDGE / 16; tile += nw) {
        const int e0 = tile * 16;
        const float* ear = edge_attr + (size_t)(e0 + colb) * 64 + krow;
        f32x4 a0 = *(const f32x4*)(ear);
        f32x4 a1 = *(const f32x4*)(ear + 4);
        f32x4 a2 = *(const f32x4*)(ear + 32);
        f32x4 a3 = *(const f32x4*)(ear + 36);
        bf16x8 Alo, Ahi;
        #pragma unroll
        for (int j = 0; j < 4; ++j) {
            Alo[j]     = f2bf(a0[j]);
            Alo[4 + j] = f2bf(a1[j]);
            Ahi[j]     = f2bf(a2[j]);
            Ahi[4 + j] = f2bf(a3[j]);
        }
        f32x4 acc[4];
        #pragma unroll
        for (int n = 0; n < 4; ++n) {
            f32x4 z = {0.f, 0.f, 0.f, 0.f};
            z = __builtin_amdgcn_mfma_f32_16x16x32_bf16(Alo, Bf[n][0], z, 0, 0, 0);
            z = __builtin_amdgcn_mfma_f32_16x16x32_bf16(Ahi, Bf[n][1], z, 0, 0, 0);
            acc[n] = z;
        }
        int srcq[4], dstq[4];
        #pragma unroll
        for (int q = 0; q < 4; ++q) {
            const int erl = (lane >> 4) * 4 + q;
            srcq[q] = ei[e0 + erl];
            dstq[q] = ei[NEDGE + e0 + erl];
        }
        float sc[4][4];
        #pragma unroll
        for (int q = 0; q < 4; ++q) {
            #pragma unroll
            for (int n = 0; n < 4; ++n) {
                const int cidx = n * 16 + colb;
                const float kv = bf2f(Kb[(size_t)srcq[q] * 64 + cidx]);
                const float qv = Qn[(size_t)dstq[q] * 64 + cidx];
                float t = kv * qv * acc[n][q];
                t += __shfl_xor(t, 1);
                t += __shfl_xor(t, 2);
                t += __shfl_xor(t, 4);
                const float s = fminf(fmaxf(t * inv_sqrt_dh, -5.0f), 5.0f);
                sc[q][n] = __expf(s);
            }
        }
        #pragma unroll
        for (int q = 0; q < 4; ++q) {
            #pragma unroll
            for (int n = 0; n < 4; ++n) {
                const int cidx = n * 16 + colb;
                const float vv = bf2f(Vb[(size_t)srcq[q] * 64 + cidx]);
                unsafeAtomicAdd(&outAcc[(size_t)dstq[q] * 64 + cidx], vv * sc[q][n]);
                if ((lane & 7) == 0) {
                    const int hh = 2 * n + b8;
                    unsafeAtomicAdd(&Z[(size_t)dstq[q] * 8 + hh], sc[q][n]);
                }
            }
        }
    }
}

__global__ void finalize_fb(float* __restrict__ out, const float* __restrict__ Z) {
    const int i = blockIdx.x * blockDim.x + threadIdx.x;
    if (i < NN * 64) {
        const int node = i >> 6;
        const int h    = (i >> 3) & 7;
        out[i] = out[i] / (Z[node * 8 + h] + 1e-6f);
    }
}

extern "C" void kernel_launch(void* const* d_in, const int* in_sizes, int n_in,
                              void* d_out, int out_size, void* d_ws, size_t ws_size,
                              hipStream_t stream) {
    const float* x         = (const float*)d_in[0];
    const float* edge_attr = (const float*)d_in[1];
    const float* WQ        = (const float*)d_in[2];
    const float* WK        = (const float*)d_in[3];
    const float* WV        = (const float*)d_in[4];
    const float* WE        = (const float*)d_in[5];
    const int*   ei        = (const int*)d_in[6];
    float* out = (float*)d_out;

    char* base = (char*)d_ws;
    float*          Qf = (float*)(base + OFF_Q);
    unsigned short* Kb = (unsigned short*)(base + OFF_KB);
    unsigned short* Vb = (unsigned short*)(base + OFF_VB);

    qkv_kernel<<<1563, 256, 0, stream>>>(x, WQ, WK, WV, Qf, Kb, Vb);

    if (ws_size >= WS_NEED) {
        int2* sorted = (int2*)(base + OFF_SRT);
        int* hist    = (int*)(base + OFF_HIST);
        int* ex      = (int*)(base + OFF_EX);
        int* bsum    = (int*)(base + OFF_BSUM);
        int* boff    = (int*)(base + OFF_BOFF);
        int* start   = (int*)(base + OFF_START);
        int* cursor  = (int*)(base + OFF_CUR);

        zero_hist_kernel<<<NB_SCAN, 256, 0, stream>>>(hist);
        hist_kernel<<<(NEDGE + 255) / 256, 256, 0, stream>>>(ei, hist);
        scanA_kernel<<<NB_SCAN, 256, 0, stream>>>(hist, ex, bsum);
        scanB_kernel<<<1, 512, 0, stream>>>(bsum, boff);
        scanC_kernel<<<(NN + 256) / 256 + 1, 256, 0, stream>>>(ex, boff, start, cursor);
        scatter_kernel<<<(NEDGE + 255) / 256, 256, 0, stream>>>(ei, cursor, sorted);
        agg_kernel<<<4096, 256, 0, stream>>>(Qf, Kb, Vb, edge_attr, WE, start, sorted, out);
    } else {
        // fallback: atomic path
        float* Z = (float*)(base + OFF_SRT);
        hipMemsetAsync(d_out, 0, (size_t)NN * 64 * sizeof(float), stream);
        hipMemsetAsync(Z, 0, (size_t)NN * 8 * sizeof(float), stream);
        edge_kernel_fb<<<2048, 256, 0, stream>>>(edge_attr, WE, Qf, Kb, Vb, ei, out, Z);
        finalize_fb<<<(NN * 64 + 255) / 256, 256, 0, stream>>>(out, Z);
    }
}